// Round 2
// baseline (897.063 us; speedup 1.0000x reference)
//
#include <hip/hip_runtime.h>
#include <hip/hip_bf16.h>
#include <math.h>

#define B_    16
#define G_    4096
#define M_    128
#define D_    768
#define GI15  0.16431676725154983f   // 0.3^1.5
#define EPS_  1e-12f

// ---------------------------------------------------------------------------
// K1a: per-(b,m) GTO column sum-of-squares over the grid axis.
// gto = d^(q-1) * exp(-z^2 d^2).  atomicAdd partials into gnorm2[B][M].
// ---------------------------------------------------------------------------
__global__ void k_gto_norm(const float* __restrict__ dist,
                           const int*   __restrict__ qn,
                           const int*   __restrict__ ao,
                           const float* __restrict__ zeta,
                           float*       __restrict__ gnorm2) {
    int b  = blockIdx.x >> 4;        // 16 g-chunks per molecule
    int gc = blockIdx.x & 15;        // 256-row chunk
    int m  = threadIdx.x & 127;
    int gh = threadIdx.x >> 7;       // 0..1
    float q  = (float)qn[b * M_ + m];
    float z  = zeta[ao[b * M_ + m]];
    float z2 = z * z;
    float acc = 0.f;
    const float* dp = dist + ((size_t)(b * G_ + gc * 256 + gh)) * M_ + m;
    #pragma unroll 4
    for (int i = 0; i < 128; ++i) {
        float d  = dp[(size_t)i * 2 * M_];
        float d2 = d * d;
        float e  = __expf(-z2 * d2);
        float p1 = (q < 1.5f) ? 1.f : ((q < 2.5f) ? d : d2);
        float g  = p1 * e;
        acc += g * g;
    }
    atomicAdd(&gnorm2[b * M_ + m], acc);
}

// ---------------------------------------------------------------------------
// K1b: per-(b,d) coefficient column sum-of-squares over m.
// ---------------------------------------------------------------------------
__global__ void k_cnorm(const int*   __restrict__ ao,
                        const float* __restrict__ table,
                        float*       __restrict__ cnorm2) {
    int b = blockIdx.y;
    int d = blockIdx.x * 256 + threadIdx.x;
    __shared__ int sao[M_];
    if (threadIdx.x < M_) sao[threadIdx.x] = ao[b * M_ + threadIdx.x];
    __syncthreads();
    float acc = 0.f;
    #pragma unroll 8
    for (int m = 0; m < M_; ++m) {
        float v = table[(size_t)sao[m] * D_ + d];
        acc += v * v;
    }
    cnorm2[b * D_ + d] = acc;
}

// ---------------------------------------------------------------------------
// K2: fused GEMM.  Per block: 64 g-rows x 64 d-cols, K = M = 128 in 8 chunks
// of 16.  A-tiles (gto & l_gto) computed on the fly from distances into LDS;
// B-tile = table[ao[m]][d] / (cnorm[d] * gdenom[m]) shared by both outputs.
// Writes raw mo -> out[0], l_mo -> out[1]; accumulates sum(mo^2) per (b,d).
// ---------------------------------------------------------------------------
#define TG   64
#define TD   64
#define KC   16
#define ASTR 68   // +4 pad keeps 16B alignment, kills staging bank conflicts

__global__ __launch_bounds__(256) void k_gemm(
        const float* __restrict__ dist,
        const int*   __restrict__ qn,
        const int*   __restrict__ ao,
        const float* __restrict__ zeta,
        const float* __restrict__ table,
        const float* __restrict__ gnorm2,
        const float* __restrict__ cnorm2,
        float*       __restrict__ out,     // [2][B*G][D]
        float*       __restrict__ mosq) {  // [B][D]
    __shared__ float sAg[KC * ASTR];
    __shared__ float sAl[KC * ASTR];
    __shared__ float sB [KC * ASTR];
    __shared__ float pm_z2[M_], pm_q[M_], pm_rg[M_];
    __shared__ int   pm_ao[M_];
    __shared__ float rcn[TD];
    __shared__ float red[16 * TD];

    const int tid = threadIdx.x;
    const int b  = blockIdx.z;
    const int g0 = blockIdx.y * TG;
    const int d0 = blockIdx.x * TD;

    if (tid < 128) {
        int m = tid;
        float q = (float)qn[b * M_ + m];
        int   a = ao[b * M_ + m];
        float z = zeta[a];
        pm_q[m]  = q;
        pm_z2[m] = z * z;
        pm_ao[m] = a;
        float gn = sqrtf(gnorm2[b * M_ + m]);
        pm_rg[m] = 1.f / (fmaxf(gn, EPS_) * GI15);
    } else if (tid < 192) {
        int dl = tid - 128;
        rcn[dl] = 1.f / fmaxf(sqrtf(cnorm2[b * D_ + d0 + dl]), EPS_);
    }
    __syncthreads();

    const int ty = tid >> 4, tx = tid & 15;       // compute mapping
    const int m_l = tid & 15, gsub = tid >> 4;    // A-stage mapping
    const int dl_ = tid & 63, msub = tid >> 6;    // B-stage mapping

    float accm[4][4], accl[4][4];
    #pragma unroll
    for (int i = 0; i < 4; ++i)
        #pragma unroll
        for (int j = 0; j < 4; ++j) { accm[i][j] = 0.f; accl[i][j] = 0.f; }

    #pragma unroll 1
    for (int kc = 0; kc < 8; ++kc) {
        // ---- stage A (gto + l_gto), coalesced rows of 16 m's ----
        {
            int m = kc * KC + m_l;
            float z2 = pm_z2[m], q = pm_q[m];
            float c4 = 4.f * z2 * z2;
            float c2 = 2.f * z2 * (2.f * q + 1.f);
            float c0 = q * (q - 1.f);
            #pragma unroll
            for (int p = 0; p < 4; ++p) {
                int g = p * 16 + gsub;
                float d  = dist[((size_t)b * G_ + g0 + g) * M_ + m];
                float d2 = d * d;
                float e  = __expf(-z2 * d2);
                float p1 = (q < 1.5f) ? 1.f : ((q < 2.5f) ? d : d2);
                float gto  = p1 * e;
                float poly = (c4 * d2 - c2) * d2 + c0;
                float lg   = (p1 / d2) * e * poly;
                sAg[m_l * ASTR + g] = gto;
                sAl[m_l * ASTR + g] = lg;
            }
        }
        // ---- stage B' = table[ao[m]][d] * rcn[d] * rg[m] ----
        #pragma unroll
        for (int p = 0; p < 4; ++p) {
            int mk = p * 4 + msub;
            int mm = kc * KC + mk;
            float v = table[(size_t)pm_ao[mm] * D_ + d0 + dl_];
            sB[mk * ASTR + dl_] = v * rcn[dl_] * pm_rg[mm];
        }
        __syncthreads();
        // ---- inner product ----
        #pragma unroll
        for (int k = 0; k < KC; ++k) {
            float4 ag = *(const float4*)&sAg[k * ASTR + ty * 4];
            float4 av = *(const float4*)&sAl[k * ASTR + ty * 4];
            float4 bv = *(const float4*)&sB [k * ASTR + tx * 4];
            float a_[4] = {ag.x, ag.y, ag.z, ag.w};
            float l_[4] = {av.x, av.y, av.z, av.w};
            float b_[4] = {bv.x, bv.y, bv.z, bv.w};
            #pragma unroll
            for (int i = 0; i < 4; ++i)
                #pragma unroll
                for (int j = 0; j < 4; ++j) {
                    accm[i][j] = fmaf(a_[i], b_[j], accm[i][j]);
                    accl[i][j] = fmaf(l_[i], b_[j], accl[i][j]);
                }
        }
        __syncthreads();
    }

    // ---- epilogue: raw writes + mosq partial reduction ----
    const size_t HALF = (size_t)B_ * G_ * D_;
    size_t base0 = ((size_t)b * G_ + g0 + ty * 4) * D_ + d0 + tx * 4;
    #pragma unroll
    for (int i = 0; i < 4; ++i) {
        float4 vm = make_float4(accm[i][0], accm[i][1], accm[i][2], accm[i][3]);
        float4 vl = make_float4(accl[i][0], accl[i][1], accl[i][2], accl[i][3]);
        *(float4*)&out[base0 + (size_t)i * D_]        = vm;
        *(float4*)&out[HALF + base0 + (size_t)i * D_] = vl;
    }
    #pragma unroll
    for (int j = 0; j < 4; ++j) {
        float s = accm[0][j] * accm[0][j] + accm[1][j] * accm[1][j]
                + accm[2][j] * accm[2][j] + accm[3][j] * accm[3][j];
        red[ty * TD + tx * 4 + j] = s;
    }
    __syncthreads();
    if (tid < TD) {
        float s = 0.f;
        #pragma unroll
        for (int r = 0; r < 16; ++r) s += red[r * TD + tid];
        atomicAdd(&mosq[b * D_ + d0 + tid], s);
    }
}

// ---------------------------------------------------------------------------
// K2.5: scale[b][d] = sqrt(Nel[b]/D) / max(sqrt(mosq[b][d]), EPS)
// ---------------------------------------------------------------------------
__global__ void k_scale(const float* __restrict__ mosq,
                        const float* __restrict__ Nel,
                        float*       __restrict__ scale) {
    int i = blockIdx.x * 256 + threadIdx.x;
    if (i >= B_ * D_) return;
    int b = i / D_;
    scale[i] = sqrtf(Nel[b] / (float)D_) / fmaxf(sqrtf(mosq[i]), EPS_);
}

// ---------------------------------------------------------------------------
// K3: in-place scale of both halves of d_out (float4-vectorized).
// ---------------------------------------------------------------------------
__global__ void k_norm(float* __restrict__ out,
                       const float* __restrict__ scale) {
    const size_t HALF4 = (size_t)B_ * G_ * D_ / 4;
    size_t stride = (size_t)gridDim.x * blockDim.x;
    for (size_t i = (size_t)blockIdx.x * blockDim.x + threadIdx.x;
         i < HALF4; i += stride) {
        size_t row = i / (D_ / 4);
        int d4 = (int)(i - row * (D_ / 4));
        int b  = (int)(row >> 12);                 // row / G_
        float4 s = *(const float4*)&scale[b * D_ + d4 * 4];
        float4* p0 = (float4*)out + i;
        float4* p1 = (float4*)out + HALF4 + i;
        float4 v0 = *p0, v1 = *p1;
        v0.x *= s.x; v0.y *= s.y; v0.z *= s.z; v0.w *= s.w;
        v1.x *= s.x; v1.y *= s.y; v1.z *= s.z; v1.w *= s.w;
        *p0 = v0; *p1 = v1;
    }
}

// ---------------------------------------------------------------------------
extern "C" void kernel_launch(void* const* d_in, const int* in_sizes, int n_in,
                              void* d_out, int out_size, void* d_ws, size_t ws_size,
                              hipStream_t stream) {
    const float* dist  = (const float*)d_in[0];
    const int*   qn    = (const int*)  d_in[1];
    const int*   ao    = (const int*)  d_in[2];
    const float* Nel   = (const float*)d_in[3];
    const float* table = (const float*)d_in[4];
    const float* zeta  = (const float*)d_in[5];
    float* out = (float*)d_out;
    float* ws  = (float*)d_ws;

    float* gnorm2 = ws;                       // [B*M]   = 2048
    float* cnorm2 = ws + 2048;                // [B*D]   = 12288
    float* mosq   = ws + 2048 + 12288;        // [B*D]
    float* scale  = ws + 2048 + 2 * 12288;    // [B*D]

    hipMemsetAsync(d_ws, 0, (size_t)(2048 + 3 * 12288) * sizeof(float), stream);

    k_gto_norm<<<256, 256, 0, stream>>>(dist, qn, ao, zeta, gnorm2);
    k_cnorm<<<dim3(3, 16), 256, 0, stream>>>(ao, table, cnorm2);
    k_gemm<<<dim3(D_ / TD, G_ / TG, B_), 256, 0, stream>>>(
        dist, qn, ao, zeta, table, gnorm2, cnorm2, out, mosq);
    k_scale<<<(B_ * D_ + 255) / 256, 256, 0, stream>>>(mosq, Nel, scale);
    k_norm<<<2048, 256, 0, stream>>>(out, scale);
}